// Round 2
// baseline (3498.417 us; speedup 1.0000x reference)
//
#include <hip/hip_runtime.h>
#include <math.h>

#define DIV_UP(a,b) (((a)+(b)-1)/(b))

static constexpr int Bb = 4, Tt = 256, Mm = 512, Dd = 1024, Vv = 50257;
static constexpr int NN = Bb * Tt;   // 1024 flattened (b,t) rows

typedef __attribute__((ext_vector_type(8))) short short8v;
typedef __attribute__((ext_vector_type(4))) float float4v;

// round-to-nearest-even fp32 -> bf16 (bit trick, branchless)
static __device__ __forceinline__ short f2bf(float f) {
    unsigned u = __float_as_uint(f);
    u += 0x7FFFu + ((u >> 16) & 1u);
    return (short)(u >> 16);
}

// ---------------------------------------------------------------------------
// bf16 MFMA GEMM (NT): C[i,j] = sum_k A[i,k]*B[j,k] + bias[j]
// A: NN x K fp32, B: V x K fp32 (converted to bf16 in staging), C: NN x V fp32
// 128x128 tile, BK=32, 256 threads = 4 waves (2x2), each wave 64x64 (4x4 frags)
// ---------------------------------------------------------------------------
__launch_bounds__(256)
__global__ void gemm_bf16nt(const float* __restrict__ A,
                            const float* __restrict__ B,
                            const float* __restrict__ bias,
                            float* __restrict__ C,
                            int Ncols, int K)
{
    __shared__ __align__(16) short As[128 * 32];   // 8 KB, [row][32] bf16
    __shared__ __align__(16) short Bs[128 * 32];   // 8 KB

    const int tid  = threadIdx.x;
    const int lane = tid & 63;
    const int wave = tid >> 6;
    const int mw = (wave >> 1) * 64;    // wave row offset in tile
    const int nw = (wave & 1) * 64;     // wave col offset in tile
    const int i0 = blockIdx.y * 128;
    const int j0 = blockIdx.x * 128;

    // staging geometry: chunk c in {0,1}: row = c*64 + tid/4, col8 = (tid&3)*8
    const int srow = tid >> 2;          // 0..63
    const int scol = (tid & 3) * 8;     // 0,8,16,24

    const int arow0 = i0 + srow;
    const int arow1 = i0 + 64 + srow;
    int brow0 = j0 + srow;        if (brow0 > Ncols - 1) brow0 = Ncols - 1;
    int brow1 = j0 + 64 + srow;   if (brow1 > Ncols - 1) brow1 = Ncols - 1;

    float4v acc[4][4];
#pragma unroll
    for (int m = 0; m < 4; ++m)
#pragma unroll
        for (int n = 0; n < 4; ++n) acc[m][n] = (float4v){0.f, 0.f, 0.f, 0.f};

    for (int k0 = 0; k0 < K; k0 += 32) {
        // ---- global loads (fp32) for this K-step
        const float* a0 = &A[(long)arow0 * K + k0 + scol];
        const float* a1 = &A[(long)arow1 * K + k0 + scol];
        const float* b0 = &B[(long)brow0 * K + k0 + scol];
        const float* b1 = &B[(long)brow1 * K + k0 + scol];
        float4 av00 = *(const float4*)(a0);
        float4 av01 = *(const float4*)(a0 + 4);
        float4 av10 = *(const float4*)(a1);
        float4 av11 = *(const float4*)(a1 + 4);
        float4 bv00 = *(const float4*)(b0);
        float4 bv01 = *(const float4*)(b0 + 4);
        float4 bv10 = *(const float4*)(b1);
        float4 bv11 = *(const float4*)(b1 + 4);

        __syncthreads();   // previous iteration's frag reads done

        short8v t;
        t[0]=f2bf(av00.x); t[1]=f2bf(av00.y); t[2]=f2bf(av00.z); t[3]=f2bf(av00.w);
        t[4]=f2bf(av01.x); t[5]=f2bf(av01.y); t[6]=f2bf(av01.z); t[7]=f2bf(av01.w);
        *(short8v*)&As[srow * 32 + scol] = t;
        t[0]=f2bf(av10.x); t[1]=f2bf(av10.y); t[2]=f2bf(av10.z); t[3]=f2bf(av10.w);
        t[4]=f2bf(av11.x); t[5]=f2bf(av11.y); t[6]=f2bf(av11.z); t[7]=f2bf(av11.w);
        *(short8v*)&As[(64 + srow) * 32 + scol] = t;
        t[0]=f2bf(bv00.x); t[1]=f2bf(bv00.y); t[2]=f2bf(bv00.z); t[3]=f2bf(bv00.w);
        t[4]=f2bf(bv01.x); t[5]=f2bf(bv01.y); t[6]=f2bf(bv01.z); t[7]=f2bf(bv01.w);
        *(short8v*)&Bs[srow * 32 + scol] = t;
        t[0]=f2bf(bv10.x); t[1]=f2bf(bv10.y); t[2]=f2bf(bv10.z); t[3]=f2bf(bv10.w);
        t[4]=f2bf(bv11.x); t[5]=f2bf(bv11.y); t[6]=f2bf(bv11.z); t[7]=f2bf(bv11.w);
        *(short8v*)&Bs[(64 + srow) * 32 + scol] = t;

        __syncthreads();   // tile ready

        // ---- fragments: lane holds X[row = base + (lane&15)][k = (lane>>4)*8 + j]
        short8v a[4], b[4];
        const int fr = lane & 15;
        const int fk = (lane >> 4) * 8;
#pragma unroll
        for (int m = 0; m < 4; ++m)
            a[m] = *(const short8v*)&As[(mw + m * 16 + fr) * 32 + fk];
#pragma unroll
        for (int n = 0; n < 4; ++n)
            b[n] = *(const short8v*)&Bs[(nw + n * 16 + fr) * 32 + fk];

#pragma unroll
        for (int m = 0; m < 4; ++m)
#pragma unroll
            for (int n = 0; n < 4; ++n)
                acc[m][n] = __builtin_amdgcn_mfma_f32_16x16x32_bf16(a[m], b[n], acc[m][n], 0, 0, 0);
    }

    // ---- epilogue: D[r][c] lane mapping: c = lane&15, r = (lane>>4)*4 + q
    const int fc = lane & 15;
    const int fq = (lane >> 4) * 4;
#pragma unroll
    for (int n = 0; n < 4; ++n) {
        const int col = j0 + nw + n * 16 + fc;
        if (col >= Ncols) continue;
        const float bc = bias[col];
#pragma unroll
        for (int m = 0; m < 4; ++m) {
            const int r0 = i0 + mw + m * 16 + fq;
            float4v v = acc[m][n];
#pragma unroll
            for (int q = 0; q < 4; ++q)
                C[(long)(r0 + q) * Ncols + col] = v[q] + bc;
        }
    }
}

// ---------------------------------------------------------------------------
// Generic tiled fp32 GEMM (unchanged from round 1; used for the small GEMMs).
// ---------------------------------------------------------------------------
template<int BM, int BN, int BK, bool BT, int ACT, bool HAS_BIAS>
__launch_bounds__(256)
__global__ void gemm_f32(const float* __restrict__ A,
                         const float* __restrict__ A2, int ksplit, int lda2,
                         const float* __restrict__ B,
                         const float* __restrict__ bias,
                         float* __restrict__ C,
                         int Ncols, int K, int lda, int ldb, int ldc,
                         long sAb, long sBb, long sCb)
{
    constexpr int TM = BM / 16;
    constexpr int TN = BN / 16;
    __shared__ float As[BK][BM + 4];
    __shared__ float Bs[BK][BN + 4];

    const int tid = threadIdx.x;
    const int tx = tid & 15;
    const int ty = tid >> 4;
    const int bz = blockIdx.z;
    const int i0 = blockIdx.y * BM;
    const int j0 = blockIdx.x * BN;

    const float* Ab  = A + (long)bz * sAb;
    const float* Bp  = B + (long)bz * sBb;

    float acc[TM][TN];
#pragma unroll
    for (int i = 0; i < TM; ++i)
#pragma unroll
        for (int j = 0; j < TN; ++j) acc[i][j] = 0.0f;

    for (int k0 = 0; k0 < K; k0 += BK) {
        const float* Asrc = Ab;
        int acol = k0, ldae = lda;
        if (k0 >= ksplit) { Asrc = A2; acol = k0 - ksplit; ldae = lda2; }

#pragma unroll
        for (int l = 0; l < (BM * BK) / 1024; ++l) {
            int idx = tid + l * 256;
            int row = idx >> 2;
            int kq  = (idx & 3) * 4;
            float4 av = *(const float4*)&Asrc[(long)(i0 + row) * ldae + acol + kq];
            As[kq + 0][row] = av.x;
            As[kq + 1][row] = av.y;
            As[kq + 2][row] = av.z;
            As[kq + 3][row] = av.w;
        }
        if (BT) {
#pragma unroll
            for (int l = 0; l < (BN * BK) / 1024; ++l) {
                int idx = tid + l * 256;
                int row = idx >> 2;
                int kq  = (idx & 3) * 4;
                float4 bv = make_float4(0.f, 0.f, 0.f, 0.f);
                if (j0 + row < Ncols)
                    bv = *(const float4*)&Bp[(long)(j0 + row) * ldb + k0 + kq];
                Bs[kq + 0][row] = bv.x;
                Bs[kq + 1][row] = bv.y;
                Bs[kq + 2][row] = bv.z;
                Bs[kq + 3][row] = bv.w;
            }
        } else {
#pragma unroll
            for (int l = 0; l < (BN * BK) / 1024; ++l) {
                int idx  = tid + l * 256;
                int krow = idx / (BN / 4);
                int c4   = (idx % (BN / 4)) * 4;
                float4 bv = make_float4(0.f, 0.f, 0.f, 0.f);
                if (j0 + c4 + 3 < Ncols) {
                    bv = *(const float4*)&Bp[(long)(k0 + krow) * ldb + j0 + c4];
                } else {
                    float t[4];
#pragma unroll
                    for (int q = 0; q < 4; ++q)
                        t[q] = (j0 + c4 + q < Ncols)
                             ? Bp[(long)(k0 + krow) * ldb + j0 + c4 + q] : 0.f;
                    bv = make_float4(t[0], t[1], t[2], t[3]);
                }
                *(float4*)&Bs[krow][c4] = bv;
            }
        }
        __syncthreads();
#pragma unroll
        for (int kk = 0; kk < BK; ++kk) {
            float a[TM], b[TN];
#pragma unroll
            for (int p = 0; p < TM / 4; ++p) {
                float4 v = *(const float4*)&As[kk][ty * TM + p * 4];
                a[p*4+0] = v.x; a[p*4+1] = v.y; a[p*4+2] = v.z; a[p*4+3] = v.w;
            }
#pragma unroll
            for (int p = 0; p < TN / 4; ++p) {
                float4 v = *(const float4*)&Bs[kk][tx * TN + p * 4];
                b[p*4+0] = v.x; b[p*4+1] = v.y; b[p*4+2] = v.z; b[p*4+3] = v.w;
            }
#pragma unroll
            for (int i = 0; i < TM; ++i)
#pragma unroll
                for (int j = 0; j < TN; ++j)
                    acc[i][j] = fmaf(a[i], b[j], acc[i][j]);
        }
        __syncthreads();
    }

    float* Cb = C + (long)bz * sCb;
#pragma unroll
    for (int i = 0; i < TM; ++i) {
        int row = i0 + ty * TM + i;
#pragma unroll
        for (int p = 0; p < TN / 4; ++p) {
            int col = j0 + tx * TN + p * 4;
            float v[4];
#pragma unroll
            for (int q = 0; q < 4; ++q) {
                float x = acc[i][p * 4 + q];
                if (HAS_BIAS && (col + q < Ncols)) x += bias[col + q];
                if (ACT == 1) x = tanhf(x);
                v[q] = x;
            }
            if (col + 3 < Ncols) {
                *(float4*)&Cb[(long)row * ldc + col] = make_float4(v[0], v[1], v[2], v[3]);
            } else {
#pragma unroll
                for (int q = 0; q < 4; ++q)
                    if (col + q < Ncols) Cb[(long)row * ldc + col + q] = v[q];
            }
        }
    }
}

// ---- masked softmax over M=512, in place; attn[m>=len]=0 ---------------------
__global__ void softmax_rows(float* __restrict__ s, const int* __restrict__ msl)
{
    __shared__ float red[256];
    const int row = blockIdx.x;
    const int b   = row / Tt;
    const int len = msl[b];
    float* p = s + (long)row * Mm;
    const int tid = threadIdx.x;

    float v[2], mx = -INFINITY;
#pragma unroll
    for (int q = 0; q < 2; ++q) {
        int m = tid + q * 256;
        v[q] = (m < len) ? p[m] : -INFINITY;
        mx = fmaxf(mx, v[q]);
    }
    red[tid] = mx; __syncthreads();
    for (int off = 128; off > 0; off >>= 1) {
        if (tid < off) red[tid] = fmaxf(red[tid], red[tid + off]);
        __syncthreads();
    }
    mx = red[0]; __syncthreads();

    float e[2], sm = 0.f;
#pragma unroll
    for (int q = 0; q < 2; ++q) {
        int m = tid + q * 256;
        e[q] = (m < len) ? expf(v[q] - mx) : 0.f;
        sm += e[q];
    }
    red[tid] = sm; __syncthreads();
    for (int off = 128; off > 0; off >>= 1) {
        if (tid < off) red[tid] += red[tid + off];
        __syncthreads();
    }
    const float inv = 1.0f / red[0];
#pragma unroll
    for (int q = 0; q < 2; ++q) p[tid + q * 256] = e[q] * inv;
}

// ---- p_gen[row] = sigmoid(dot(dwa[row], Wg) + bg) ---------------------------
__global__ void pgen_kernel(const float* __restrict__ dwa, const float* __restrict__ Wg,
                            const float* __restrict__ bg, float* __restrict__ pg)
{
    __shared__ float red[256];
    const int row = blockIdx.x;
    const float* x = dwa + (long)row * Dd;
    const int tid = threadIdx.x;
    float s = 0.f;
#pragma unroll
    for (int q = 0; q < 4; ++q) {
        int d = tid + q * 256;
        s += x[d] * Wg[d];
    }
    red[tid] = s; __syncthreads();
    for (int off = 128; off > 0; off >>= 1) {
        if (tid < off) red[tid] += red[tid + off];
        __syncthreads();
    }
    if (tid == 0) pg[row] = 1.0f / (1.0f + expf(-(red[0] + bg[0])));
}

// ---- per-row max then sum(exp) over V (two-pass; 2nd read is L2/L3-hot) -----
__global__ void rowstats2(const float* __restrict__ logits,
                          float* __restrict__ rowmax, float* __restrict__ rowsum)
{
    __shared__ float red[256];
    const int row = blockIdx.x;
    const float* p = logits + (long)row * Vv;
    const int tid = threadIdx.x;

    float mx = -INFINITY;
    for (int v = tid; v < Vv; v += 256) mx = fmaxf(mx, p[v]);
    red[tid] = mx; __syncthreads();
    for (int off = 128; off > 0; off >>= 1) {
        if (tid < off) red[tid] = fmaxf(red[tid], red[tid + off]);
        __syncthreads();
    }
    mx = red[0]; __syncthreads();

    float sm = 0.f;
    for (int v = tid; v < Vv; v += 256) sm += __expf(p[v] - mx);
    red[tid] = sm; __syncthreads();
    for (int off = 128; off > 0; off >>= 1) {
        if (tid < off) red[tid] += red[tid + off];
        __syncthreads();
    }
    if (tid == 0) { rowmax[row] = mx; rowsum[row] = red[0]; }
}

// ---- fused scale + copy-scatter + log, one block per row --------------------
// final[v] = log( exp(l[v]-mx)*pg/sum + sum_{m:ids[m]==v} attn[m]*(1-pg) )
// non-hit entries: log(exp(a)*inv) = a + log(inv)  (no transcendentals needed)
__launch_bounds__(256)
__global__ void finalize_kernel(float* __restrict__ out, const float* __restrict__ attn,
                                const float* __restrict__ pg, const int* __restrict__ ids,
                                const int* __restrict__ msl,
                                const float* __restrict__ rowmax, const float* __restrict__ rowsum)
{
    constexpr int BMW = DIV_UP(Vv, 32);      // bitmap words
    __shared__ unsigned bm[BMW];
    __shared__ int   ids_s[Mm];
    __shared__ float vals_s[Mm];

    const int row = blockIdx.x;
    const int b   = row / Tt;
    const int len = msl[b];
    const int tid = threadIdx.x;

    const float pgen = pg[row];
    const float c    = 1.0f - pgen;
    const float inv  = pgen / rowsum[row];
    const float mx   = rowmax[row];
    const float linv = __logf(inv);

    for (int w = tid; w < BMW; w += 256) bm[w] = 0u;
    __syncthreads();
    for (int m = tid; m < len; m += 256) {
        int id = ids[(long)b * Mm + m];
        ids_s[m]  = id;
        vals_s[m] = attn[(long)row * Mm + m] * c;
        atomicOr(&bm[id >> 5], 1u << (id & 31));
    }
    __syncthreads();

    float* p = out + (long)row * Vv;
    for (int v = tid; v < Vv; v += 256) {
        float a = p[v] - mx;
        float r;
        if ((bm[v >> 5] >> (v & 31)) & 1u) {
            float x = __expf(a) * inv;
            for (int m = 0; m < len; ++m)
                if (ids_s[m] == v) x += vals_s[m];
            r = __logf(x);
        } else {
            r = a + linv;
        }
        p[v] = r;
    }
}

extern "C" void kernel_launch(void* const* d_in, const int* in_sizes, int n_in,
                              void* d_out, int out_size, void* d_ws, size_t ws_size,
                              hipStream_t stream)
{
    const float* dec = (const float*)d_in[0];
    const float* mem = (const float*)d_in[1];
    const int*   msl = (const int*)d_in[2];
    const int*   ids = (const int*)d_in[3];
    const float* Wc  = (const float*)d_in[4];
    // d_in[5] = b_copy: per-(b,t)-constant shift of scores -> softmax-invariant; skip.
    const float* Wd  = (const float*)d_in[6];
    const float* bd  = (const float*)d_in[7];
    const float* Wg  = (const float*)d_in[8];
    const float* bg  = (const float*)d_in[9];
    const float* Wo  = (const float*)d_in[10];
    const float* bo  = (const float*)d_in[11];

    float* out = (float*)d_out;
    float* ws     = (float*)d_ws;
    float* attn   = ws;                          // NN*Mm
    float* pg     = attn + (size_t)NN * Mm;      // NN
    float* rowmax = pg + NN;                     // NN
    float* rowsum = rowmax + NN;                 // NN
    // d_out doubles as scratch before the logits GEMM overwrites all of it
    float* dec_proj = out;                       // NN*Dd
    float* attn_out = out + (size_t)NN * Dd;     // NN*Dd
    float* dwa      = out + (size_t)2 * NN * Dd; // NN*Dd

    // 1. dec_proj = dec @ W_copy                (NN x Dd x Dd)
    gemm_f32<64,64,16,false,0,false><<<dim3(Dd/64, NN/64, 1), 256, 0, stream>>>(
        dec, dec, Dd, Dd, Wc, nullptr, dec_proj, Dd, Dd, Dd, Dd, Dd, 0, 0, 0);

    // 2. scores[b] = dec_proj[b] @ mem[b]^T     (batched NT, Tt x Mm x Dd)
    gemm_f32<64,64,16,true,0,false><<<dim3(Mm/64, Tt/64, Bb), 256, 0, stream>>>(
        dec_proj, dec_proj, Dd, Dd, mem, nullptr, attn, Mm, Dd, Dd, Dd, Mm,
        (long)Tt*Dd, (long)Mm*Dd, (long)Tt*Mm);

    // 3. masked softmax
    softmax_rows<<<NN, 256, 0, stream>>>(attn, msl);

    // 4. attn_out[b] = attn[b] @ mem[b]         (batched NN, Tt x Dd x Mm)
    gemm_f32<64,64,16,false,0,false><<<dim3(Dd/64, Tt/64, Bb), 256, 0, stream>>>(
        attn, attn, Mm, Mm, mem, nullptr, attn_out, Dd, Mm, Mm, Dd, Dd,
        (long)Tt*Mm, (long)Mm*Dd, (long)Tt*Dd);

    // 5. dwa = tanh([dec|attn_out] @ W_dec^T + b_dec)   (split-A NT, K=2048)
    gemm_f32<64,64,16,true,1,true><<<dim3(Dd/64, NN/64, 1), 256, 0, stream>>>(
        dec, attn_out, Dd, Dd, Wd, bd, dwa, Dd, 2*Dd, Dd, 2*Dd, Dd, 0, 0, 0);

    // 6. p_gen
    pgen_kernel<<<NN, 256, 0, stream>>>(dwa, Wg, bg, pg);

    // 7. logits = dec @ W_out^T + b_out  -> d_out (bf16 MFMA, the hot kernel)
    gemm_bf16nt<<<dim3(DIV_UP(Vv,128), NN/128, 1), 256, 0, stream>>>(
        dec, Wo, bo, out, Vv, Dd);

    // 8. per-row max / sumexp
    rowstats2<<<NN, 256, 0, stream>>>(out, rowmax, rowsum);

    // 9. fused scale + copy + log
    finalize_kernel<<<NN, 256, 0, stream>>>(out, attn, pg, ids, msl, rowmax, rowsum);
}

// Round 3
// 1119.432 us; speedup vs baseline: 3.1252x; 3.1252x over previous
//
#include <hip/hip_runtime.h>
#include <math.h>

#define DIV_UP(a,b) (((a)+(b)-1)/(b))

static constexpr int Bb = 4, Tt = 256, Mm = 512, Dd = 1024, Vv = 50257;
static constexpr int NN = Bb * Tt;   // 1024 flattened (b,t) rows

typedef __attribute__((ext_vector_type(8))) short short8v;
typedef __attribute__((ext_vector_type(4))) float float4v;

// round-to-nearest-even fp32 -> bf16 (bit trick, branchless)
static __device__ __forceinline__ short f2bf(float f) {
    unsigned u = __float_as_uint(f);
    u += 0x7FFFu + ((u >> 16) & 1u);
    return (short)(u >> 16);
}

// ---------------------------------------------------------------------------
// bf16 MFMA GEMM (NT): C[i,j] = sum_k A[i,k]*B[j,k] + bias[j]
// Also accumulates rowsum[i] += sum_j exp(C[i,j]) via shuffle-reduce+atomics.
// (Logits are small -- |l|<~5 -- so exp without max-subtraction is safe.)
// 128x128 tile, BK=32, 256 threads = 4 waves (2x2), each wave 64x64 (4x4 frags)
// ---------------------------------------------------------------------------
__launch_bounds__(256)
__global__ void gemm_bf16nt(const float* __restrict__ A,
                            const float* __restrict__ B,
                            const float* __restrict__ bias,
                            float* __restrict__ C,
                            float* __restrict__ rowsum,
                            int Ncols, int K)
{
    __shared__ __align__(16) short As[128 * 32];   // 8 KB, [row][32] bf16
    __shared__ __align__(16) short Bs[128 * 32];   // 8 KB

    const int tid  = threadIdx.x;
    const int lane = tid & 63;
    const int wave = tid >> 6;
    const int mw = (wave >> 1) * 64;    // wave row offset in tile
    const int nw = (wave & 1) * 64;     // wave col offset in tile
    const int i0 = blockIdx.y * 128;
    const int j0 = blockIdx.x * 128;

    const int srow = tid >> 2;          // 0..63
    const int scol = (tid & 3) * 8;     // 0,8,16,24

    const int arow0 = i0 + srow;
    const int arow1 = i0 + 64 + srow;
    int brow0 = j0 + srow;        if (brow0 > Ncols - 1) brow0 = Ncols - 1;
    int brow1 = j0 + 64 + srow;   if (brow1 > Ncols - 1) brow1 = Ncols - 1;

    float4v acc[4][4];
#pragma unroll
    for (int m = 0; m < 4; ++m)
#pragma unroll
        for (int n = 0; n < 4; ++n) acc[m][n] = (float4v){0.f, 0.f, 0.f, 0.f};

    for (int k0 = 0; k0 < K; k0 += 32) {
        const float* a0 = &A[(long)arow0 * K + k0 + scol];
        const float* a1 = &A[(long)arow1 * K + k0 + scol];
        const float* b0 = &B[(long)brow0 * K + k0 + scol];
        const float* b1 = &B[(long)brow1 * K + k0 + scol];
        float4 av00 = *(const float4*)(a0);
        float4 av01 = *(const float4*)(a0 + 4);
        float4 av10 = *(const float4*)(a1);
        float4 av11 = *(const float4*)(a1 + 4);
        float4 bv00 = *(const float4*)(b0);
        float4 bv01 = *(const float4*)(b0 + 4);
        float4 bv10 = *(const float4*)(b1);
        float4 bv11 = *(const float4*)(b1 + 4);

        __syncthreads();   // previous iteration's frag reads done

        short8v t;
        t[0]=f2bf(av00.x); t[1]=f2bf(av00.y); t[2]=f2bf(av00.z); t[3]=f2bf(av00.w);
        t[4]=f2bf(av01.x); t[5]=f2bf(av01.y); t[6]=f2bf(av01.z); t[7]=f2bf(av01.w);
        *(short8v*)&As[srow * 32 + scol] = t;
        t[0]=f2bf(av10.x); t[1]=f2bf(av10.y); t[2]=f2bf(av10.z); t[3]=f2bf(av10.w);
        t[4]=f2bf(av11.x); t[5]=f2bf(av11.y); t[6]=f2bf(av11.z); t[7]=f2bf(av11.w);
        *(short8v*)&As[(64 + srow) * 32 + scol] = t;
        t[0]=f2bf(bv00.x); t[1]=f2bf(bv00.y); t[2]=f2bf(bv00.z); t[3]=f2bf(bv00.w);
        t[4]=f2bf(bv01.x); t[5]=f2bf(bv01.y); t[6]=f2bf(bv01.z); t[7]=f2bf(bv01.w);
        *(short8v*)&Bs[srow * 32 + scol] = t;
        t[0]=f2bf(bv10.x); t[1]=f2bf(bv10.y); t[2]=f2bf(bv10.z); t[3]=f2bf(bv10.w);
        t[4]=f2bf(bv11.x); t[5]=f2bf(bv11.y); t[6]=f2bf(bv11.z); t[7]=f2bf(bv11.w);
        *(short8v*)&Bs[(64 + srow) * 32 + scol] = t;

        __syncthreads();   // tile ready

        short8v a[4], b[4];
        const int fr = lane & 15;
        const int fk = (lane >> 4) * 8;
#pragma unroll
        for (int m = 0; m < 4; ++m)
            a[m] = *(const short8v*)&As[(mw + m * 16 + fr) * 32 + fk];
#pragma unroll
        for (int n = 0; n < 4; ++n)
            b[n] = *(const short8v*)&Bs[(nw + n * 16 + fr) * 32 + fk];

#pragma unroll
        for (int m = 0; m < 4; ++m)
#pragma unroll
            for (int n = 0; n < 4; ++n)
                acc[m][n] = __builtin_amdgcn_mfma_f32_16x16x32_bf16(a[m], b[n], acc[m][n], 0, 0, 0);
    }

    // ---- epilogue: D[r][c] lane mapping: c = lane&15, r = (lane>>4)*4 + q
    const int fc = lane & 15;
    const int fq = (lane >> 4) * 4;
    float rsum[4][4];
#pragma unroll
    for (int m = 0; m < 4; ++m)
#pragma unroll
        for (int q = 0; q < 4; ++q) rsum[m][q] = 0.f;

#pragma unroll
    for (int n = 0; n < 4; ++n) {
        const int col = j0 + nw + n * 16 + fc;
        if (col >= Ncols) continue;
        const float bc = bias[col];
#pragma unroll
        for (int m = 0; m < 4; ++m) {
            const int r0 = i0 + mw + m * 16 + fq;
            float4v v = acc[m][n];
#pragma unroll
            for (int q = 0; q < 4; ++q) {
                float x = v[q] + bc;
                C[(long)(r0 + q) * Ncols + col] = x;
                rsum[m][q] += __expf(x);
            }
        }
    }
    // reduce rsum across the 16-lane column group (lanes g*16..g*16+15)
#pragma unroll
    for (int m = 0; m < 4; ++m)
#pragma unroll
        for (int q = 0; q < 4; ++q) {
            float s = rsum[m][q];
            s += __shfl_xor(s, 1);
            s += __shfl_xor(s, 2);
            s += __shfl_xor(s, 4);
            s += __shfl_xor(s, 8);
            if (fc == 0)
                atomicAdd(&rowsum[i0 + mw + m * 16 + fq + q], s);
        }
}

// ---------------------------------------------------------------------------
// Generic tiled fp32 GEMM (small GEMMs).
// ---------------------------------------------------------------------------
template<int BM, int BN, int BK, bool BT, int ACT, bool HAS_BIAS>
__launch_bounds__(256)
__global__ void gemm_f32(const float* __restrict__ A,
                         const float* __restrict__ A2, int ksplit, int lda2,
                         const float* __restrict__ B,
                         const float* __restrict__ bias,
                         float* __restrict__ C,
                         int Ncols, int K, int lda, int ldb, int ldc,
                         long sAb, long sBb, long sCb)
{
    constexpr int TM = BM / 16;
    constexpr int TN = BN / 16;
    __shared__ float As[BK][BM + 4];
    __shared__ float Bs[BK][BN + 4];

    const int tid = threadIdx.x;
    const int tx = tid & 15;
    const int ty = tid >> 4;
    const int bz = blockIdx.z;
    const int i0 = blockIdx.y * BM;
    const int j0 = blockIdx.x * BN;

    const float* Ab  = A + (long)bz * sAb;
    const float* Bp  = B + (long)bz * sBb;

    float acc[TM][TN];
#pragma unroll
    for (int i = 0; i < TM; ++i)
#pragma unroll
        for (int j = 0; j < TN; ++j) acc[i][j] = 0.0f;

    for (int k0 = 0; k0 < K; k0 += BK) {
        const float* Asrc = Ab;
        int acol = k0, ldae = lda;
        if (k0 >= ksplit) { Asrc = A2; acol = k0 - ksplit; ldae = lda2; }

#pragma unroll
        for (int l = 0; l < (BM * BK) / 1024; ++l) {
            int idx = tid + l * 256;
            int row = idx >> 2;
            int kq  = (idx & 3) * 4;
            float4 av = *(const float4*)&Asrc[(long)(i0 + row) * ldae + acol + kq];
            As[kq + 0][row] = av.x;
            As[kq + 1][row] = av.y;
            As[kq + 2][row] = av.z;
            As[kq + 3][row] = av.w;
        }
        if (BT) {
#pragma unroll
            for (int l = 0; l < (BN * BK) / 1024; ++l) {
                int idx = tid + l * 256;
                int row = idx >> 2;
                int kq  = (idx & 3) * 4;
                float4 bv = make_float4(0.f, 0.f, 0.f, 0.f);
                if (j0 + row < Ncols)
                    bv = *(const float4*)&Bp[(long)(j0 + row) * ldb + k0 + kq];
                Bs[kq + 0][row] = bv.x;
                Bs[kq + 1][row] = bv.y;
                Bs[kq + 2][row] = bv.z;
                Bs[kq + 3][row] = bv.w;
            }
        } else {
#pragma unroll
            for (int l = 0; l < (BN * BK) / 1024; ++l) {
                int idx  = tid + l * 256;
                int krow = idx / (BN / 4);
                int c4   = (idx % (BN / 4)) * 4;
                float4 bv = make_float4(0.f, 0.f, 0.f, 0.f);
                if (j0 + c4 + 3 < Ncols) {
                    bv = *(const float4*)&Bp[(long)(k0 + krow) * ldb + j0 + c4];
                } else {
                    float t[4];
#pragma unroll
                    for (int q = 0; q < 4; ++q)
                        t[q] = (j0 + c4 + q < Ncols)
                             ? Bp[(long)(k0 + krow) * ldb + j0 + c4 + q] : 0.f;
                    bv = make_float4(t[0], t[1], t[2], t[3]);
                }
                *(float4*)&Bs[krow][c4] = bv;
            }
        }
        __syncthreads();
#pragma unroll
        for (int kk = 0; kk < BK; ++kk) {
            float a[TM], b[TN];
#pragma unroll
            for (int p = 0; p < TM / 4; ++p) {
                float4 v = *(const float4*)&As[kk][ty * TM + p * 4];
                a[p*4+0] = v.x; a[p*4+1] = v.y; a[p*4+2] = v.z; a[p*4+3] = v.w;
            }
#pragma unroll
            for (int p = 0; p < TN / 4; ++p) {
                float4 v = *(const float4*)&Bs[kk][tx * TN + p * 4];
                b[p*4+0] = v.x; b[p*4+1] = v.y; b[p*4+2] = v.z; b[p*4+3] = v.w;
            }
#pragma unroll
            for (int i = 0; i < TM; ++i)
#pragma unroll
                for (int j = 0; j < TN; ++j)
                    acc[i][j] = fmaf(a[i], b[j], acc[i][j]);
        }
        __syncthreads();
    }

    float* Cb = C + (long)bz * sCb;
#pragma unroll
    for (int i = 0; i < TM; ++i) {
        int row = i0 + ty * TM + i;
#pragma unroll
        for (int p = 0; p < TN / 4; ++p) {
            int col = j0 + tx * TN + p * 4;
            float v[4];
#pragma unroll
            for (int q = 0; q < 4; ++q) {
                float x = acc[i][p * 4 + q];
                if (HAS_BIAS && (col + q < Ncols)) x += bias[col + q];
                if (ACT == 1) x = tanhf(x);
                v[q] = x;
            }
            if (col + 3 < Ncols) {
                *(float4*)&Cb[(long)row * ldc + col] = make_float4(v[0], v[1], v[2], v[3]);
            } else {
#pragma unroll
                for (int q = 0; q < 4; ++q)
                    if (col + q < Ncols) Cb[(long)row * ldc + col + q] = v[q];
            }
        }
    }
}

// ---- masked softmax over M=512, in place; attn[m>=len]=0 ---------------------
__global__ void softmax_rows(float* __restrict__ s, const int* __restrict__ msl)
{
    __shared__ float red[256];
    const int row = blockIdx.x;
    const int b   = row / Tt;
    const int len = msl[b];
    float* p = s + (long)row * Mm;
    const int tid = threadIdx.x;

    float v[2], mx = -INFINITY;
#pragma unroll
    for (int q = 0; q < 2; ++q) {
        int m = tid + q * 256;
        v[q] = (m < len) ? p[m] : -INFINITY;
        mx = fmaxf(mx, v[q]);
    }
    red[tid] = mx; __syncthreads();
    for (int off = 128; off > 0; off >>= 1) {
        if (tid < off) red[tid] = fmaxf(red[tid], red[tid + off]);
        __syncthreads();
    }
    mx = red[0]; __syncthreads();

    float e[2], sm = 0.f;
#pragma unroll
    for (int q = 0; q < 2; ++q) {
        int m = tid + q * 256;
        e[q] = (m < len) ? expf(v[q] - mx) : 0.f;
        sm += e[q];
    }
    red[tid] = sm; __syncthreads();
    for (int off = 128; off > 0; off >>= 1) {
        if (tid < off) red[tid] += red[tid + off];
        __syncthreads();
    }
    const float inv = 1.0f / red[0];
#pragma unroll
    for (int q = 0; q < 2; ++q) p[tid + q * 256] = e[q] * inv;
}

// ---- p_gen[row] = sigmoid(dot(dwa[row], Wg) + bg); also zeroes rowsum -------
__global__ void pgen_kernel(const float* __restrict__ dwa, const float* __restrict__ Wg,
                            const float* __restrict__ bg, float* __restrict__ pg,
                            float* __restrict__ rowsum)
{
    __shared__ float red[256];
    const int row = blockIdx.x;
    const float* x = dwa + (long)row * Dd;
    const int tid = threadIdx.x;
    float s = 0.f;
#pragma unroll
    for (int q = 0; q < 4; ++q) {
        int d = tid + q * 256;
        s += x[d] * Wg[d];
    }
    red[tid] = s; __syncthreads();
    for (int off = 128; off > 0; off >>= 1) {
        if (tid < off) red[tid] += red[tid + off];
        __syncthreads();
    }
    if (tid == 0) {
        pg[row] = 1.0f / (1.0f + expf(-(red[0] + bg[0])));
        rowsum[row] = 0.0f;      // cleared before gemm_bf16nt accumulates
    }
}

// ---- linv[row] = log(pg/rowsum) --------------------------------------------
__global__ void linv_kernel(const float* __restrict__ pg, const float* __restrict__ rowsum,
                            float* __restrict__ linv)
{
    int i = blockIdx.x * 256 + threadIdx.x;
    if (i < NN) linv[i] = __logf(pg[i] / rowsum[i]);
}

// ---- out[i] += linv[row]  (flat float4 streaming; per-component row) --------
__launch_bounds__(256)
__global__ void shift_kernel(float* __restrict__ out, const float* __restrict__ linv)
{
    constexpr long TOT4 = (long)NN * Vv / 4;   // divisible: NN*Vv % 4 == 0
    float4* p = (float4*)out;
    for (long i4 = blockIdx.x * 256 + threadIdx.x; i4 < TOT4; i4 += (long)gridDim.x * 256) {
        float4 v = p[i4];
        unsigned base = (unsigned)(i4 * 4);
        v.x += linv[(base    ) / (unsigned)Vv];
        v.y += linv[(base + 1) / (unsigned)Vv];
        v.z += linv[(base + 2) / (unsigned)Vv];
        v.w += linv[(base + 3) / (unsigned)Vv];
        p[i4] = v;
    }
}

// ---- per-row copy fix-up: out[id] = log(exp(out[id]) + total_copy[id]) ------
// First-occurrence dedupe handles repeated memory_ids within a row.
__launch_bounds__(256)
__global__ void fixup_kernel(float* __restrict__ out, const float* __restrict__ attn,
                             const float* __restrict__ pg, const int* __restrict__ ids,
                             const int* __restrict__ msl)
{
    __shared__ int   ids_s[Mm];
    __shared__ float vals_s[Mm];
    const int row = blockIdx.x;
    const int b   = row / Tt;
    const int len = msl[b];
    const int tid = threadIdx.x;
    const float c = 1.0f - pg[row];

    for (int m = tid; m < len; m += 256) {
        ids_s[m]  = ids[(long)b * Mm + m];
        vals_s[m] = attn[(long)row * Mm + m] * c;
    }
    __syncthreads();

    float* p = out + (long)row * Vv;
    for (int m = tid; m < len; m += 256) {
        const int id = ids_s[m];
        bool first = true;
        float tot = vals_s[m];
        for (int m2 = 0; m2 < len; ++m2) {
            if (ids_s[m2] == id) {
                if (m2 < m) { first = false; break; }
                if (m2 > m) tot += vals_s[m2];
            }
        }
        if (first) p[id] = __logf(__expf(p[id]) + tot);
    }
}

extern "C" void kernel_launch(void* const* d_in, const int* in_sizes, int n_in,
                              void* d_out, int out_size, void* d_ws, size_t ws_size,
                              hipStream_t stream)
{
    const float* dec = (const float*)d_in[0];
    const float* mem = (const float*)d_in[1];
    const int*   msl = (const int*)d_in[2];
    const int*   ids = (const int*)d_in[3];
    const float* Wc  = (const float*)d_in[4];
    // d_in[5] = b_copy: per-(b,t)-constant shift of scores -> softmax-invariant; skip.
    const float* Wd  = (const float*)d_in[6];
    const float* bd  = (const float*)d_in[7];
    const float* Wg  = (const float*)d_in[8];
    const float* bg  = (const float*)d_in[9];
    const float* Wo  = (const float*)d_in[10];
    const float* bo  = (const float*)d_in[11];

    float* out = (float*)d_out;
    float* ws     = (float*)d_ws;
    float* attn   = ws;                          // NN*Mm
    float* pg     = attn + (size_t)NN * Mm;      // NN
    float* linv   = pg + NN;                     // NN
    float* rowsum = linv + NN;                   // NN
    // d_out doubles as scratch before the logits GEMM overwrites all of it
    float* dec_proj = out;                       // NN*Dd
    float* attn_out = out + (size_t)NN * Dd;     // NN*Dd
    float* dwa      = out + (size_t)2 * NN * Dd; // NN*Dd

    // 1. dec_proj = dec @ W_copy                (NN x Dd x Dd)
    gemm_f32<64,64,16,false,0,false><<<dim3(Dd/64, NN/64, 1), 256, 0, stream>>>(
        dec, dec, Dd, Dd, Wc, nullptr, dec_proj, Dd, Dd, Dd, Dd, Dd, 0, 0, 0);

    // 2. scores[b] = dec_proj[b] @ mem[b]^T     (batched NT, Tt x Mm x Dd)
    gemm_f32<64,64,16,true,0,false><<<dim3(Mm/64, Tt/64, Bb), 256, 0, stream>>>(
        dec_proj, dec_proj, Dd, Dd, mem, nullptr, attn, Mm, Dd, Dd, Dd, Mm,
        (long)Tt*Dd, (long)Mm*Dd, (long)Tt*Mm);

    // 3. masked softmax
    softmax_rows<<<NN, 256, 0, stream>>>(attn, msl);

    // 4. attn_out[b] = attn[b] @ mem[b]         (batched NN, Tt x Dd x Mm)
    gemm_f32<64,64,16,false,0,false><<<dim3(Dd/64, Tt/64, Bb), 256, 0, stream>>>(
        attn, attn, Mm, Mm, mem, nullptr, attn_out, Dd, Mm, Mm, Dd, Dd,
        (long)Tt*Mm, (long)Mm*Dd, (long)Tt*Dd);

    // 5. dwa = tanh([dec|attn_out] @ W_dec^T + b_dec)   (split-A NT, K=2048)
    gemm_f32<64,64,16,true,1,true><<<dim3(Dd/64, NN/64, 1), 256, 0, stream>>>(
        dec, attn_out, Dd, Dd, Wd, bd, dwa, Dd, 2*Dd, Dd, 2*Dd, Dd, 0, 0, 0);

    // 6. p_gen (+ zero rowsum before the GEMM's atomics)
    pgen_kernel<<<NN, 256, 0, stream>>>(dwa, Wg, bg, pg, rowsum);

    // 7. logits = dec @ W_out^T + b_out -> d_out; rowsum += per-row sum(exp)
    gemm_bf16nt<<<dim3(DIV_UP(Vv,128), NN/128, 1), 256, 0, stream>>>(
        dec, Wo, bo, out, rowsum, Vv, Dd);

    // 8. linv = log(pg / rowsum)
    linv_kernel<<<DIV_UP(NN,256), 256, 0, stream>>>(pg, rowsum, linv);

    // 9. streaming shift: out += linv[row]   (non-hit entries now final)
    shift_kernel<<<4096, 256, 0, stream>>>(out, linv);

    // 10. copy fix-up on <=512 positions per row
    fixup_kernel<<<NN, 256, 0, stream>>>(out, attn, pg, ids, msl);
}

// Round 4
// 924.809 us; speedup vs baseline: 3.7829x; 1.2104x over previous
//
#include <hip/hip_runtime.h>
#include <math.h>

#define DIV_UP(a,b) (((a)+(b)-1)/(b))

static constexpr int Bb = 4, Tt = 256, Mm = 512, Dd = 1024, Vv = 50257;
static constexpr int NN = Bb * Tt;   // 1024 flattened (b,t) rows

typedef __attribute__((ext_vector_type(8))) short short8v;
typedef __attribute__((ext_vector_type(4))) float float4v;
typedef unsigned short ushort;

// round-to-nearest-even fp32 -> bf16 (bit trick, branchless)
static __device__ __forceinline__ ushort f2bf(float f) {
    unsigned u = __float_as_uint(f);
    u += 0x7FFFu + ((u >> 16) & 1u);
    return (ushort)(u >> 16);
}

// async 16B global -> LDS (direct, no VGPR round-trip)
static __device__ __forceinline__ void gload16(const void* g, void* l) {
    __builtin_amdgcn_global_load_lds(
        (const __attribute__((address_space(1))) unsigned int*)g,
        (__attribute__((address_space(3))) unsigned int*)l, 16, 0, 0);
}

// ---- fp32 -> bf16 cast, 8 elems/thread, grid-stride -------------------------
__launch_bounds__(256)
__global__ void cast_bf16(const float* __restrict__ src, ushort* __restrict__ dst, long n8)
{
    for (long i = blockIdx.x * 256 + threadIdx.x; i < n8; i += (long)gridDim.x * 256) {
        const float4 v0 = *(const float4*)&src[i * 8];
        const float4 v1 = *(const float4*)&src[i * 8 + 4];
        short8v t;
        t[0]=f2bf(v0.x); t[1]=f2bf(v0.y); t[2]=f2bf(v0.z); t[3]=f2bf(v0.w);
        t[4]=f2bf(v1.x); t[5]=f2bf(v1.y); t[6]=f2bf(v1.z); t[7]=f2bf(v1.w);
        *(short8v*)&dst[i * 8] = t;
    }
}

// ---------------------------------------------------------------------------
// bf16 MFMA GEMM (NT), pre-cast bf16 inputs, global_load_lds staging.
// C[i,j] = sum_k A[i,k]*B[j,k] + bias[j]; rowsum[i] += sum_j exp(C[i,j]).
// 128x128 tile, BK=32, 256 threads = 4 waves (2x2), wave = 64x64 (4x4 frags).
// grid: x = M-tiles (8, fast axis -> B-tile reuse in L2/L3), y = N-tiles (393)
// ---------------------------------------------------------------------------
__launch_bounds__(256)
__global__ void gemm_bf16lds(const ushort* __restrict__ A,
                             const ushort* __restrict__ B,
                             const float* __restrict__ bias,
                             float* __restrict__ C,
                             float* __restrict__ rowsum,
                             int Ncols, int K)
{
    __shared__ __align__(16) ushort As[128 * 32];   // 8 KB, [row][32] bf16
    __shared__ __align__(16) ushort Bs[128 * 32];   // 8 KB

    const int tid  = threadIdx.x;
    const int lane = tid & 63;
    const int wave = tid >> 6;
    const int mw = (wave >> 1) * 64;
    const int nw = (wave & 1) * 64;
    const int i0 = blockIdx.x * 128;     // M fast axis
    const int j0 = blockIdx.y * 128;

    // staging: chunk r in {0,1}: idx = r*256+tid covers row idx/4, 8-bf16 piece idx%4
    const int srow0 = tid >> 2;          // rows 0..63   (r=0)
    const int srow1 = 64 + srow0;        // rows 64..127 (r=1)
    const int spos  = (tid & 3) * 8;     // bf16 offset within row

    const long arow0 = i0 + srow0;
    const long arow1 = i0 + srow1;
    long brow0 = j0 + srow0; if (brow0 > Vv - 1) brow0 = Vv - 1;
    long brow1 = j0 + srow1; if (brow1 > Vv - 1) brow1 = Vv - 1;

    // LDS dest: linear in tid*16 bytes (wave-uniform base + lane*16) — required layout
    ushort* asd0 = &As[(long)tid * 8];           // = As + (r*256+tid)*8 elems, r=0
    ushort* asd1 = &As[(256 + (long)tid) * 8];
    ushort* bsd0 = &Bs[(long)tid * 8];
    ushort* bsd1 = &Bs[(256 + (long)tid) * 8];

    float4v acc[4][4];
#pragma unroll
    for (int m = 0; m < 4; ++m)
#pragma unroll
        for (int n = 0; n < 4; ++n) acc[m][n] = (float4v){0.f, 0.f, 0.f, 0.f};

    for (int k0 = 0; k0 < K; k0 += 32) {
        __syncthreads();   // previous iteration's frag reads done
        gload16(&A[arow0 * K + k0 + spos], asd0);
        gload16(&A[arow1 * K + k0 + spos], asd1);
        gload16(&B[brow0 * K + k0 + spos], bsd0);
        gload16(&B[brow1 * K + k0 + spos], bsd1);
        __syncthreads();   // drains vmcnt -> tile ready

        short8v a[4], b[4];
        const int fr = lane & 15;
        const int fk = (lane >> 4) * 8;
#pragma unroll
        for (int m = 0; m < 4; ++m)
            a[m] = *(const short8v*)&As[(mw + m * 16 + fr) * 32 + fk];
#pragma unroll
        for (int n = 0; n < 4; ++n)
            b[n] = *(const short8v*)&Bs[(nw + n * 16 + fr) * 32 + fk];

#pragma unroll
        for (int m = 0; m < 4; ++m)
#pragma unroll
            for (int n = 0; n < 4; ++n)
                acc[m][n] = __builtin_amdgcn_mfma_f32_16x16x32_bf16(a[m], b[n], acc[m][n], 0, 0, 0);
    }

    // epilogue: D[r][c]: c = lane&15, r = (lane>>4)*4 + q
    const int fc = lane & 15;
    const int fq = (lane >> 4) * 4;
    float rsum[4][4];
#pragma unroll
    for (int m = 0; m < 4; ++m)
#pragma unroll
        for (int q = 0; q < 4; ++q) rsum[m][q] = 0.f;

#pragma unroll
    for (int n = 0; n < 4; ++n) {
        const int col = j0 + nw + n * 16 + fc;
        if (col >= Ncols) continue;
        const float bc = bias[col];
#pragma unroll
        for (int m = 0; m < 4; ++m) {
            const int r0 = i0 + mw + m * 16 + fq;
            float4v v = acc[m][n];
#pragma unroll
            for (int q = 0; q < 4; ++q) {
                float x = v[q] + bc;
                C[(long)(r0 + q) * Ncols + col] = x;
                rsum[m][q] += __expf(x);
            }
        }
    }
#pragma unroll
    for (int m = 0; m < 4; ++m)
#pragma unroll
        for (int q = 0; q < 4; ++q) {
            float s = rsum[m][q];
            s += __shfl_xor(s, 1);
            s += __shfl_xor(s, 2);
            s += __shfl_xor(s, 4);
            s += __shfl_xor(s, 8);
            if (fc == 0)
                atomicAdd(&rowsum[i0 + mw + m * 16 + fq + q], s);
        }
}

// ---------------------------------------------------------------------------
// Fallback: reg-staged bf16 GEMM from fp32 inputs (used when ws too small).
// Same math/epilogue; grid also (M-tiles fast, N-tiles slow).
// ---------------------------------------------------------------------------
__launch_bounds__(256)
__global__ void gemm_bf16nt(const float* __restrict__ A,
                            const float* __restrict__ B,
                            const float* __restrict__ bias,
                            float* __restrict__ C,
                            float* __restrict__ rowsum,
                            int Ncols, int K)
{
    __shared__ __align__(16) ushort As[128 * 32];
    __shared__ __align__(16) ushort Bs[128 * 32];

    const int tid  = threadIdx.x;
    const int lane = tid & 63;
    const int wave = tid >> 6;
    const int mw = (wave >> 1) * 64;
    const int nw = (wave & 1) * 64;
    const int i0 = blockIdx.x * 128;
    const int j0 = blockIdx.y * 128;

    const int srow = tid >> 2;
    const int scol = (tid & 3) * 8;

    const int arow0 = i0 + srow;
    const int arow1 = i0 + 64 + srow;
    int brow0 = j0 + srow;        if (brow0 > Ncols - 1) brow0 = Ncols - 1;
    int brow1 = j0 + 64 + srow;   if (brow1 > Ncols - 1) brow1 = Ncols - 1;

    float4v acc[4][4];
#pragma unroll
    for (int m = 0; m < 4; ++m)
#pragma unroll
        for (int n = 0; n < 4; ++n) acc[m][n] = (float4v){0.f, 0.f, 0.f, 0.f};

    for (int k0 = 0; k0 < K; k0 += 32) {
        const float* a0 = &A[(long)arow0 * K + k0 + scol];
        const float* a1 = &A[(long)arow1 * K + k0 + scol];
        const float* b0 = &B[(long)brow0 * K + k0 + scol];
        const float* b1 = &B[(long)brow1 * K + k0 + scol];
        float4 av00 = *(const float4*)(a0);
        float4 av01 = *(const float4*)(a0 + 4);
        float4 av10 = *(const float4*)(a1);
        float4 av11 = *(const float4*)(a1 + 4);
        float4 bv00 = *(const float4*)(b0);
        float4 bv01 = *(const float4*)(b0 + 4);
        float4 bv10 = *(const float4*)(b1);
        float4 bv11 = *(const float4*)(b1 + 4);

        __syncthreads();

        short8v t;
        t[0]=f2bf(av00.x); t[1]=f2bf(av00.y); t[2]=f2bf(av00.z); t[3]=f2bf(av00.w);
        t[4]=f2bf(av01.x); t[5]=f2bf(av01.y); t[6]=f2bf(av01.z); t[7]=f2bf(av01.w);
        *(short8v*)&As[srow * 32 + scol] = t;
        t[0]=f2bf(av10.x); t[1]=f2bf(av10.y); t[2]=f2bf(av10.z); t[3]=f2bf(av10.w);
        t[4]=f2bf(av11.x); t[5]=f2bf(av11.y); t[6]=f2bf(av11.z); t[7]=f2bf(av11.w);
        *(short8v*)&As[(64 + srow) * 32 + scol] = t;
        t[0]=f2bf(bv00.x); t[1]=f2bf(bv00.y); t[2]=f2bf(bv00.z); t[3]=f2bf(bv00.w);
        t[4]=f2bf(bv01.x); t[5]=f2bf(bv01.y); t[6]=f2bf(bv01.z); t[7]=f2bf(bv01.w);
        *(short8v*)&Bs[srow * 32 + scol] = t;
        t[0]=f2bf(bv10.x); t[1]=f2bf(bv10.y); t[2]=f2bf(bv10.z); t[3]=f2bf(bv10.w);
        t[4]=f2bf(bv11.x); t[5]=f2bf(bv11.y); t[6]=f2bf(bv11.z); t[7]=f2bf(bv11.w);
        *(short8v*)&Bs[(64 + srow) * 32 + scol] = t;

        __syncthreads();

        short8v a[4], b[4];
        const int fr = lane & 15;
        const int fk = (lane >> 4) * 8;
#pragma unroll
        for (int m = 0; m < 4; ++m)
            a[m] = *(const short8v*)&As[(mw + m * 16 + fr) * 32 + fk];
#pragma unroll
        for (int n = 0; n < 4; ++n)
            b[n] = *(const short8v*)&Bs[(nw + n * 16 + fr) * 32 + fk];

#pragma unroll
        for (int m = 0; m < 4; ++m)
#pragma unroll
            for (int n = 0; n < 4; ++n)
                acc[m][n] = __builtin_amdgcn_mfma_f32_16x16x32_bf16(a[m], b[n], acc[m][n], 0, 0, 0);
    }

    const int fc = lane & 15;
    const int fq = (lane >> 4) * 4;
    float rsum[4][4];
#pragma unroll
    for (int m = 0; m < 4; ++m)
#pragma unroll
        for (int q = 0; q < 4; ++q) rsum[m][q] = 0.f;

#pragma unroll
    for (int n = 0; n < 4; ++n) {
        const int col = j0 + nw + n * 16 + fc;
        if (col >= Ncols) continue;
        const float bc = bias[col];
#pragma unroll
        for (int m = 0; m < 4; ++m) {
            const int r0 = i0 + mw + m * 16 + fq;
            float4v v = acc[m][n];
#pragma unroll
            for (int q = 0; q < 4; ++q) {
                float x = v[q] + bc;
                C[(long)(r0 + q) * Ncols + col] = x;
                rsum[m][q] += __expf(x);
            }
        }
    }
#pragma unroll
    for (int m = 0; m < 4; ++m)
#pragma unroll
        for (int q = 0; q < 4; ++q) {
            float s = rsum[m][q];
            s += __shfl_xor(s, 1);
            s += __shfl_xor(s, 2);
            s += __shfl_xor(s, 4);
            s += __shfl_xor(s, 8);
            if (fc == 0)
                atomicAdd(&rowsum[i0 + mw + m * 16 + fq + q], s);
        }
}

// ---------------------------------------------------------------------------
// Generic tiled fp32 GEMM (small GEMMs).
// ---------------------------------------------------------------------------
template<int BM, int BN, int BK, bool BT, int ACT, bool HAS_BIAS>
__launch_bounds__(256)
__global__ void gemm_f32(const float* __restrict__ A,
                         const float* __restrict__ A2, int ksplit, int lda2,
                         const float* __restrict__ B,
                         const float* __restrict__ bias,
                         float* __restrict__ C,
                         int Ncols, int K, int lda, int ldb, int ldc,
                         long sAb, long sBb, long sCb)
{
    constexpr int TM = BM / 16;
    constexpr int TN = BN / 16;
    __shared__ float As[BK][BM + 4];
    __shared__ float Bs[BK][BN + 4];

    const int tid = threadIdx.x;
    const int tx = tid & 15;
    const int ty = tid >> 4;
    const int bz = blockIdx.z;
    const int i0 = blockIdx.y * BM;
    const int j0 = blockIdx.x * BN;

    const float* Ab  = A + (long)bz * sAb;
    const float* Bp  = B + (long)bz * sBb;

    float acc[TM][TN];
#pragma unroll
    for (int i = 0; i < TM; ++i)
#pragma unroll
        for (int j = 0; j < TN; ++j) acc[i][j] = 0.0f;

    for (int k0 = 0; k0 < K; k0 += BK) {
        const float* Asrc = Ab;
        int acol = k0, ldae = lda;
        if (k0 >= ksplit) { Asrc = A2; acol = k0 - ksplit; ldae = lda2; }

#pragma unroll
        for (int l = 0; l < (BM * BK) / 1024; ++l) {
            int idx = tid + l * 256;
            int row = idx >> 2;
            int kq  = (idx & 3) * 4;
            float4 av = *(const float4*)&Asrc[(long)(i0 + row) * ldae + acol + kq];
            As[kq + 0][row] = av.x;
            As[kq + 1][row] = av.y;
            As[kq + 2][row] = av.z;
            As[kq + 3][row] = av.w;
        }
        if (BT) {
#pragma unroll
            for (int l = 0; l < (BN * BK) / 1024; ++l) {
                int idx = tid + l * 256;
                int row = idx >> 2;
                int kq  = (idx & 3) * 4;
                float4 bv = make_float4(0.f, 0.f, 0.f, 0.f);
                if (j0 + row < Ncols)
                    bv = *(const float4*)&Bp[(long)(j0 + row) * ldb + k0 + kq];
                Bs[kq + 0][row] = bv.x;
                Bs[kq + 1][row] = bv.y;
                Bs[kq + 2][row] = bv.z;
                Bs[kq + 3][row] = bv.w;
            }
        } else {
#pragma unroll
            for (int l = 0; l < (BN * BK) / 1024; ++l) {
                int idx  = tid + l * 256;
                int krow = idx / (BN / 4);
                int c4   = (idx % (BN / 4)) * 4;
                float4 bv = make_float4(0.f, 0.f, 0.f, 0.f);
                if (j0 + c4 + 3 < Ncols) {
                    bv = *(const float4*)&Bp[(long)(k0 + krow) * ldb + j0 + c4];
                } else {
                    float t[4];
#pragma unroll
                    for (int q = 0; q < 4; ++q)
                        t[q] = (j0 + c4 + q < Ncols)
                             ? Bp[(long)(k0 + krow) * ldb + j0 + c4 + q] : 0.f;
                    bv = make_float4(t[0], t[1], t[2], t[3]);
                }
                *(float4*)&Bs[krow][c4] = bv;
            }
        }
        __syncthreads();
#pragma unroll
        for (int kk = 0; kk < BK; ++kk) {
            float a[TM], b[TN];
#pragma unroll
            for (int p = 0; p < TM / 4; ++p) {
                float4 v = *(const float4*)&As[kk][ty * TM + p * 4];
                a[p*4+0] = v.x; a[p*4+1] = v.y; a[p*4+2] = v.z; a[p*4+3] = v.w;
            }
#pragma unroll
            for (int p = 0; p < TN / 4; ++p) {
                float4 v = *(const float4*)&Bs[kk][tx * TN + p * 4];
                b[p*4+0] = v.x; b[p*4+1] = v.y; b[p*4+2] = v.z; b[p*4+3] = v.w;
            }
#pragma unroll
            for (int i = 0; i < TM; ++i)
#pragma unroll
                for (int j = 0; j < TN; ++j)
                    acc[i][j] = fmaf(a[i], b[j], acc[i][j]);
        }
        __syncthreads();
    }

    float* Cb = C + (long)bz * sCb;
#pragma unroll
    for (int i = 0; i < TM; ++i) {
        int row = i0 + ty * TM + i;
#pragma unroll
        for (int p = 0; p < TN / 4; ++p) {
            int col = j0 + tx * TN + p * 4;
            float v[4];
#pragma unroll
            for (int q = 0; q < 4; ++q) {
                float x = acc[i][p * 4 + q];
                if (HAS_BIAS && (col + q < Ncols)) x += bias[col + q];
                if (ACT == 1) x = tanhf(x);
                v[q] = x;
            }
            if (col + 3 < Ncols) {
                *(float4*)&Cb[(long)row * ldc + col] = make_float4(v[0], v[1], v[2], v[3]);
            } else {
#pragma unroll
                for (int q = 0; q < 4; ++q)
                    if (col + q < Ncols) Cb[(long)row * ldc + col + q] = v[q];
            }
        }
    }
}

// ---- masked softmax over M=512, in place; attn[m>=len]=0 ---------------------
__global__ void softmax_rows(float* __restrict__ s, const int* __restrict__ msl)
{
    __shared__ float red[256];
    const int row = blockIdx.x;
    const int b   = row / Tt;
    const int len = msl[b];
    float* p = s + (long)row * Mm;
    const int tid = threadIdx.x;

    float v[2], mx = -INFINITY;
#pragma unroll
    for (int q = 0; q < 2; ++q) {
        int m = tid + q * 256;
        v[q] = (m < len) ? p[m] : -INFINITY;
        mx = fmaxf(mx, v[q]);
    }
    red[tid] = mx; __syncthreads();
    for (int off = 128; off > 0; off >>= 1) {
        if (tid < off) red[tid] = fmaxf(red[tid], red[tid + off]);
        __syncthreads();
    }
    mx = red[0]; __syncthreads();

    float e[2], sm = 0.f;
#pragma unroll
    for (int q = 0; q < 2; ++q) {
        int m = tid + q * 256;
        e[q] = (m < len) ? expf(v[q] - mx) : 0.f;
        sm += e[q];
    }
    red[tid] = sm; __syncthreads();
    for (int off = 128; off > 0; off >>= 1) {
        if (tid < off) red[tid] += red[tid + off];
        __syncthreads();
    }
    const float inv = 1.0f / red[0];
#pragma unroll
    for (int q = 0; q < 2; ++q) p[tid + q * 256] = e[q] * inv;
}

// ---- p_gen[row] = sigmoid(dot(dwa[row], Wg) + bg); also zeroes rowsum -------
__global__ void pgen_kernel(const float* __restrict__ dwa, const float* __restrict__ Wg,
                            const float* __restrict__ bg, float* __restrict__ pg,
                            float* __restrict__ rowsum)
{
    __shared__ float red[256];
    const int row = blockIdx.x;
    const float* x = dwa + (long)row * Dd;
    const int tid = threadIdx.x;
    float s = 0.f;
#pragma unroll
    for (int q = 0; q < 4; ++q) {
        int d = tid + q * 256;
        s += x[d] * Wg[d];
    }
    red[tid] = s; __syncthreads();
    for (int off = 128; off > 0; off >>= 1) {
        if (tid < off) red[tid] += red[tid + off];
        __syncthreads();
    }
    if (tid == 0) {
        pg[row] = 1.0f / (1.0f + expf(-(red[0] + bg[0])));
        rowsum[row] = 0.0f;      // cleared before the logits GEMM accumulates
    }
}

// ---- linv[row] = log(pg/rowsum) --------------------------------------------
__global__ void linv_kernel(const float* __restrict__ pg, const float* __restrict__ rowsum,
                            float* __restrict__ linv)
{
    int i = blockIdx.x * 256 + threadIdx.x;
    if (i < NN) linv[i] = __logf(pg[i] / rowsum[i]);
}

// ---- out[row][*] += linv[row], one block per row (no integer division) ------
__launch_bounds__(256)
__global__ void shift_kernel(float* __restrict__ out, const float* __restrict__ linv)
{
    const int row = blockIdx.x;
    const float s = linv[row];
    float* p = out + (long)row * Vv;
    const int tid = threadIdx.x;

    const int mis  = (int)(((unsigned)((long)row * Vv)) & 3u);  // fp32 elems past 16B boundary
    const int head = (4 - mis) & 3;
    if (tid < head) p[tid] += s;

    const int nv = (Vv - head) >> 2;
    float4* p4 = (float4*)(p + head);
    for (int i = tid; i < nv; i += 256) {
        float4 v = p4[i];
        v.x += s; v.y += s; v.z += s; v.w += s;
        p4[i] = v;
    }
    const int t = head + nv * 4 + tid;
    if (t < Vv) p[t] += s;
}

// ---- per-row copy fix-up: out[id] = log(exp(out[id]) + total_copy[id]) ------
__launch_bounds__(256)
__global__ void fixup_kernel(float* __restrict__ out, const float* __restrict__ attn,
                             const float* __restrict__ pg, const int* __restrict__ ids,
                             const int* __restrict__ msl)
{
    __shared__ int   ids_s[Mm];
    __shared__ float vals_s[Mm];
    const int row = blockIdx.x;
    const int b   = row / Tt;
    const int len = msl[b];
    const int tid = threadIdx.x;
    const float c = 1.0f - pg[row];

    for (int m = tid; m < len; m += 256) {
        ids_s[m]  = ids[(long)b * Mm + m];
        vals_s[m] = attn[(long)row * Mm + m] * c;
    }
    __syncthreads();

    float* p = out + (long)row * Vv;
    for (int m = tid; m < len; m += 256) {
        const int id = ids_s[m];
        bool first = true;
        float tot = vals_s[m];
        for (int m2 = 0; m2 < len; ++m2) {
            if (ids_s[m2] == id) {
                if (m2 < m) { first = false; break; }
                if (m2 > m) tot += vals_s[m2];
            }
        }
        if (first) p[id] = __logf(__expf(p[id]) + tot);
    }
}

extern "C" void kernel_launch(void* const* d_in, const int* in_sizes, int n_in,
                              void* d_out, int out_size, void* d_ws, size_t ws_size,
                              hipStream_t stream)
{
    const float* dec = (const float*)d_in[0];
    const float* mem = (const float*)d_in[1];
    const int*   msl = (const int*)d_in[2];
    const int*   ids = (const int*)d_in[3];
    const float* Wc  = (const float*)d_in[4];
    // d_in[5] = b_copy: per-(b,t)-constant shift of scores -> softmax-invariant; skip.
    const float* Wd  = (const float*)d_in[6];
    const float* bd  = (const float*)d_in[7];
    const float* Wg  = (const float*)d_in[8];
    const float* bg  = (const float*)d_in[9];
    const float* Wo  = (const float*)d_in[10];
    const float* bo  = (const float*)d_in[11];

    float* out = (float*)d_out;
    float* ws     = (float*)d_ws;
    float* attn   = ws;                          // NN*Mm floats
    float* pg     = attn + (size_t)NN * Mm;      // NN
    float* linv   = pg + NN;                     // NN
    float* rowsum = linv + NN;                   // NN
    ushort* A16   = (ushort*)(rowsum + NN);      // NN*Dd bf16 (16B-aligned)
    ushort* B16   = A16 + (size_t)NN * Dd;       // Vv*Dd bf16
    const size_t ws_need = (size_t)(B16 + (size_t)Vv * Dd - (ushort*)ws) * 2 / 2
                         + ((char*)B16 - (char*)ws) * 0;  // see below
    const size_t need_bytes = ((char*)(B16 + (size_t)Vv * Dd)) - (char*)ws;
    const bool fast = ws_size >= need_bytes;
    (void)ws_need;

    // d_out doubles as scratch before the logits GEMM overwrites all of it
    float* dec_proj = out;                       // NN*Dd
    float* attn_out = out + (size_t)NN * Dd;     // NN*Dd
    float* dwa      = out + (size_t)2 * NN * Dd; // NN*Dd

    // 0. pre-cast dec and W_out to bf16 (once per call; RNE, same as staging did)
    if (fast) {
        cast_bf16<<<512, 256, 0, stream>>>(dec, A16, (long)NN * Dd / 8);
        cast_bf16<<<4096, 256, 0, stream>>>(Wo, B16, (long)Vv * Dd / 8);
    }

    // 1. dec_proj = dec @ W_copy                (NN x Dd x Dd)
    gemm_f32<64,64,16,false,0,false><<<dim3(Dd/64, NN/64, 1), 256, 0, stream>>>(
        dec, dec, Dd, Dd, Wc, nullptr, dec_proj, Dd, Dd, Dd, Dd, Dd, 0, 0, 0);

    // 2. scores[b] = dec_proj[b] @ mem[b]^T     (batched NT, Tt x Mm x Dd)
    gemm_f32<64,64,16,true,0,false><<<dim3(Mm/64, Tt/64, Bb), 256, 0, stream>>>(
        dec_proj, dec_proj, Dd, Dd, mem, nullptr, attn, Mm, Dd, Dd, Dd, Mm,
        (long)Tt*Dd, (long)Mm*Dd, (long)Tt*Mm);

    // 3. masked softmax
    softmax_rows<<<NN, 256, 0, stream>>>(attn, msl);

    // 4. attn_out[b] = attn[b] @ mem[b]         (batched NN, Tt x Dd x Mm)
    gemm_f32<64,64,16,false,0,false><<<dim3(Dd/64, Tt/64, Bb), 256, 0, stream>>>(
        attn, attn, Mm, Mm, mem, nullptr, attn_out, Dd, Mm, Mm, Dd, Dd,
        (long)Tt*Mm, (long)Mm*Dd, (long)Tt*Dd);

    // 5. dwa = tanh([dec|attn_out] @ W_dec^T + b_dec)   (split-A NT, K=2048)
    gemm_f32<64,64,16,true,1,true><<<dim3(Dd/64, NN/64, 1), 256, 0, stream>>>(
        dec, attn_out, Dd, Dd, Wd, bd, dwa, Dd, 2*Dd, Dd, 2*Dd, Dd, 0, 0, 0);

    // 6. p_gen (+ zero rowsum before the GEMM's atomics)
    pgen_kernel<<<NN, 256, 0, stream>>>(dwa, Wg, bg, pg, rowsum);

    // 7. logits = dec @ W_out^T + b_out -> d_out; rowsum += per-row sum(exp)
    //    grid: M-tiles on x (fast) so the 8 sharers of each B-tile run together
    if (fast) {
        gemm_bf16lds<<<dim3(NN/128, DIV_UP(Vv,128), 1), 256, 0, stream>>>(
            A16, B16, bo, out, rowsum, Vv, Dd);
    } else {
        gemm_bf16nt<<<dim3(NN/128, DIV_UP(Vv,128), 1), 256, 0, stream>>>(
            dec, Wo, bo, out, rowsum, Vv, Dd);
    }

    // 8. linv = log(pg / rowsum)
    linv_kernel<<<DIV_UP(NN,256), 256, 0, stream>>>(pg, rowsum, linv);

    // 9. streaming shift: out += linv[row]   (non-hit entries now final)
    shift_kernel<<<NN, 256, 0, stream>>>(out, linv);

    // 10. copy fix-up on <=512 positions per row
    fixup_kernel<<<NN, 256, 0, stream>>>(out, attn, pg, ids, msl);
}

// Round 5
// 717.930 us; speedup vs baseline: 4.8729x; 1.2882x over previous
//
#include <hip/hip_runtime.h>
#include <math.h>

#define DIV_UP(a,b) (((a)+(b)-1)/(b))

static constexpr int Bb = 4, Tt = 256, Mm = 512, Dd = 1024, Vv = 50257;
static constexpr int NN = Bb * Tt;   // 1024 flattened (b,t) rows

typedef __attribute__((ext_vector_type(8))) short short8v;
typedef __attribute__((ext_vector_type(4))) float float4v;
typedef unsigned short ushort;

// fp32 -> bf16 RNE (bit trick, branchless)
static __device__ __forceinline__ ushort f2bf(float f) {
    unsigned u = __float_as_uint(f);
    u += 0x7FFFu + ((u >> 16) & 1u);
    return (ushort)(u >> 16);
}
static __device__ __forceinline__ float bf2f(ushort h) {
    return __uint_as_float(((unsigned)h) << 16);
}

// async 16B global -> LDS (wave-uniform base + lane*16 dest)
static __device__ __forceinline__ void gload16(const void* g, void* l) {
    __builtin_amdgcn_global_load_lds(
        (const __attribute__((address_space(1))) unsigned int*)g,
        (__attribute__((address_space(3))) unsigned int*)l, 16, 0, 0);
}

// ---- fp32 -> bf16 cast, 8/thread --------------------------------------------
__launch_bounds__(256)
__global__ void cast_bf16(const float* __restrict__ src, ushort* __restrict__ dst, long n8)
{
    for (long i = blockIdx.x * 256 + threadIdx.x; i < n8; i += (long)gridDim.x * 256) {
        const float4 v0 = *(const float4*)&src[i * 8];
        const float4 v1 = *(const float4*)&src[i * 8 + 4];
        short8v t;
        t[0]=f2bf(v0.x); t[1]=f2bf(v0.y); t[2]=f2bf(v0.z); t[3]=f2bf(v0.w);
        t[4]=f2bf(v1.x); t[5]=f2bf(v1.y); t[6]=f2bf(v1.z); t[7]=f2bf(v1.w);
        *(short8v*)&dst[i * 8] = t;
    }
}

// ---- fp32 -> (hi, lo) bf16 split, 8/thread ----------------------------------
__launch_bounds__(256)
__global__ void split_cast(const float* __restrict__ src, ushort* __restrict__ hi,
                           ushort* __restrict__ lo, long n8)
{
    for (long i = blockIdx.x * 256 + threadIdx.x; i < n8; i += (long)gridDim.x * 256) {
        short8v th, tl;
#pragma unroll
        for (int q = 0; q < 8; ++q) {
            float v = src[i * 8 + q];
            ushort h = f2bf(v);
            th[q] = h;
            tl[q] = f2bf(v - bf2f(h));
        }
        *(short8v*)&hi[i * 8] = th;
        *(short8v*)&lo[i * 8] = tl;
    }
}

// ---- batched transpose: in[b] R x C fp32 -> out[b] C x R bf16 (hi, opt lo) --
__launch_bounds__(256)
__global__ void transpose_split(const float* __restrict__ in, ushort* __restrict__ oh,
                                ushort* __restrict__ ol, int R, int C)
{
    __shared__ float t[32][33];
    const int bz = blockIdx.z;
    in += (long)bz * R * C;
    oh += (long)bz * R * C;
    if (ol) ol += (long)bz * R * C;
    const int tx = threadIdx.x & 31, ty = threadIdx.x >> 5;
    const int r0 = blockIdx.y * 32, c0 = blockIdx.x * 32;
#pragma unroll
    for (int k = 0; k < 4; ++k)
        t[ty + k * 8][tx] = in[(long)(r0 + ty + k * 8) * C + c0 + tx];
    __syncthreads();
#pragma unroll
    for (int k = 0; k < 4; ++k) {
        float v = t[tx][ty + k * 8];
        ushort h = f2bf(v);
        long o = (long)(c0 + ty + k * 8) * R + r0 + tx;
        oh[o] = h;
        if (ol) ol[o] = f2bf(v - bf2f(h));
    }
}

// ---------------------------------------------------------------------------
// Unified bf16 MFMA GEMM (NT): C[i,j] = sum_k A[i,k]*B[j,k]
// SPLIT: 3-pass split-bf16 (Ah*Bh + Ah*Bl + Al*Bh) for near-fp32 accuracy.
// Double-buffered LDS via global_load_lds; source addresses pre-swizzled so
// ds_read_b128 fragment reads are bank-balanced (slot ^= (row>>1)&3).
// A2/ksplit: rows read from A2 for k >= ksplit (concat input, non-split only).
// epi: 0 = fp32 C (+bias); 1 = fp32 C + bias + rowsum[i] += sum_j exp(x)
//      2 = pgacc[i] += sum_j tanh(x + bias[j]) * Wg[j]  (no C write)
//      4 = bf16 C write
// xcd_jtiles > 0: flat-grid XCD swizzle (8 M-tiles fast per XCD chunk).
// ---------------------------------------------------------------------------
template<bool SPLIT>
__launch_bounds__(256)
__global__ void gemm_mx(const ushort* __restrict__ Ah, const ushort* __restrict__ Al,
                        const ushort* __restrict__ Bh, const ushort* __restrict__ Bl,
                        const ushort* __restrict__ A2, int ksplit, int lda2,
                        const float* __restrict__ bias,
                        float* __restrict__ Cf, ushort* __restrict__ C16,
                        float* __restrict__ aux, const float* __restrict__ Wg,
                        int Ncols, int K, int lda, int ldb, int ldc,
                        long sA, long sB, long sC, int epi, int xcd_jtiles)
{
    constexpr int TILE = 4096;   // ushorts per 128x32 bf16 tile (8 KB)
    __shared__ __align__(16) ushort lds[SPLIT ? 8 * TILE : 4 * TILE];

    int mt, jt, bz;
    if (xcd_jtiles > 0) {
        const int id = blockIdx.x;
        const int s = id >> 3;
        jt = (id & 7) * ((xcd_jtiles + 7) >> 3) + (s >> 3);
        mt = s & 7;                       // 8 M-tiles, fast within XCD chunk
        bz = 0;
        if (jt >= xcd_jtiles) return;
    } else { jt = blockIdx.x; mt = blockIdx.y; bz = blockIdx.z; }

    const int tid  = threadIdx.x;
    const int lane = tid & 63;
    const int wave = tid >> 6;
    const int mw = (wave >> 1) * 64, nw = (wave & 1) * 64;
    const int i0 = mt * 128, j0 = jt * 128;

    // staging geometry: thread covers row tid/4 (+64 for chunk 1), k-slot tid&3
    const int srow = tid >> 2;
    const int soff = ((tid & 3) ^ ((srow >> 1) & 3)) * 8;   // swizzled source slot

    const long Ab = (long)bz * sA;
    const long Bz = (long)bz * sB;
    const long ar0 = i0 + srow, ar1 = i0 + 64 + srow;
    long br0 = j0 + srow;      if (br0 > Ncols - 1) br0 = Ncols - 1;
    long br1 = j0 + 64 + srow; if (br1 > Ncols - 1) br1 = Ncols - 1;

    const int NT = K >> 5;

    float4v acc[4][4];
#pragma unroll
    for (int m = 0; m < 4; ++m)
#pragma unroll
        for (int n = 0; n < 4; ++n) acc[m][n] = (float4v){0.f, 0.f, 0.f, 0.f};

#define STG(dst, src, kc) \
    gload16(&(src)[ar0 * lA + (kc) + soff], (dst) + tid * 8); \
    gload16(&(src)[ar1 * lA + (kc) + soff], (dst) + 2048 + tid * 8);
#define STGB(dst, src, kc) \
    gload16(&(src)[br0 * ldb + (kc) + soff], (dst) + tid * 8); \
    gload16(&(src)[br1 * ldb + (kc) + soff], (dst) + 2048 + tid * 8);

    // ---- stage K-window kc into buffer `buf`
#define STAGE_ALL(buf, kc)                                                     \
    {                                                                          \
        const bool sec = (kc) >= ksplit;                                       \
        const int  kk  = sec ? (kc) - ksplit : (kc);                           \
        const int  lA  = sec ? lda2 : lda;                                     \
        constexpr int BS = SPLIT ? 4 * TILE : 2 * TILE;                        \
        ushort* dA = lds + (buf) * BS;                                         \
        if (SPLIT) {                                                           \
            STG(dA, Ah + Ab, kk);                                              \
            STG(dA + TILE, Al + Ab, kk);                                       \
            STGB(dA + 2 * TILE, Bh + Bz, kc);                                  \
            STGB(dA + 3 * TILE, Bl + Bz, kc);                                  \
        } else {                                                               \
            const ushort* As = sec ? A2 : Ah;                                  \
            STG(dA, As + Ab, kk);                                              \
            STGB(dA + TILE, Bh + Bz, kc);                                      \
        }                                                                      \
    }

    STAGE_ALL(0, 0);
    __syncthreads();

    const int fr = lane & 15;
    const int rdsw = (((lane >> 4) ^ ((fr >> 1) & 3))) * 8;  // swizzled read slot

    for (int t = 0; t < NT; ++t) {
        const int cur = t & 1;
        constexpr int BS = SPLIT ? 4 * TILE : 2 * TILE;
        const ushort* Acur = lds + cur * BS;
        const ushort* Bcur = Acur + (SPLIT ? 2 * TILE : TILE);

        if (t + 1 < NT) STAGE_ALL(cur ^ 1, (t + 1) * 32);

        short8v a[4], b[4];
#pragma unroll
        for (int m = 0; m < 4; ++m)
            a[m] = *(const short8v*)&Acur[(mw + m * 16 + fr) * 32 + rdsw];
#pragma unroll
        for (int n = 0; n < 4; ++n)
            b[n] = *(const short8v*)&Bcur[(nw + n * 16 + fr) * 32 + rdsw];

        if (SPLIT) {
            short8v al[4], bl[4];
#pragma unroll
            for (int m = 0; m < 4; ++m)
                al[m] = *(const short8v*)&Acur[TILE + (mw + m * 16 + fr) * 32 + rdsw];
#pragma unroll
            for (int n = 0; n < 4; ++n)
                bl[n] = *(const short8v*)&Bcur[TILE + (nw + n * 16 + fr) * 32 + rdsw];
#pragma unroll
            for (int m = 0; m < 4; ++m)
#pragma unroll
                for (int n = 0; n < 4; ++n) {
                    acc[m][n] = __builtin_amdgcn_mfma_f32_16x16x32_bf16(a[m],  b[n],  acc[m][n], 0, 0, 0);
                    acc[m][n] = __builtin_amdgcn_mfma_f32_16x16x32_bf16(a[m],  bl[n], acc[m][n], 0, 0, 0);
                    acc[m][n] = __builtin_amdgcn_mfma_f32_16x16x32_bf16(al[m], b[n],  acc[m][n], 0, 0, 0);
                }
        } else {
#pragma unroll
            for (int m = 0; m < 4; ++m)
#pragma unroll
                for (int n = 0; n < 4; ++n)
                    acc[m][n] = __builtin_amdgcn_mfma_f32_16x16x32_bf16(a[m], b[n], acc[m][n], 0, 0, 0);
        }
        __syncthreads();
    }
#undef STAGE_ALL
#undef STGB
#undef STG

    // ---- epilogue: D[r][c]: c = lane&15, r = (lane>>4)*4 + q
    const int fc = lane & 15;
    const int fq = (lane >> 4) * 4;
    float red[4][4];
#pragma unroll
    for (int m = 0; m < 4; ++m)
#pragma unroll
        for (int q = 0; q < 4; ++q) red[m][q] = 0.f;

#pragma unroll
    for (int n = 0; n < 4; ++n) {
        const int col = j0 + nw + n * 16 + fc;
        if (col >= Ncols) continue;
        const float bc = bias ? bias[col] : 0.f;
        const float wg = (epi == 2) ? Wg[col] : 0.f;
#pragma unroll
        for (int m = 0; m < 4; ++m) {
            const int r0 = i0 + mw + m * 16 + fq;
            float4v v = acc[m][n];
#pragma unroll
            for (int q = 0; q < 4; ++q) {
                float x = v[q] + bc;
                if (epi == 0) {
                    Cf[(long)bz * sC + (long)(r0 + q) * ldc + col] = x;
                } else if (epi == 1) {
                    Cf[(long)(r0 + q) * ldc + col] = x;
                    red[m][q] += __expf(x);
                } else if (epi == 2) {
                    red[m][q] += tanhf(x) * wg;
                } else {
                    C16[(long)bz * sC + (long)(r0 + q) * ldc + col] = f2bf(x);
                }
            }
        }
    }
    if (epi == 1 || epi == 2) {
#pragma unroll
        for (int m = 0; m < 4; ++m)
#pragma unroll
            for (int q = 0; q < 4; ++q) {
                float s = red[m][q];
                s += __shfl_xor(s, 1);
                s += __shfl_xor(s, 2);
                s += __shfl_xor(s, 4);
                s += __shfl_xor(s, 8);
                if (fc == 0)
                    atomicAdd(&aux[i0 + mw + m * 16 + fq + q], s);
            }
    }
}

// ---- masked softmax over M=512, in place; attn[m>=len]=0 --------------------
__global__ void softmax_rows(float* __restrict__ s, const int* __restrict__ msl)
{
    __shared__ float red[256];
    const int row = blockIdx.x;
    const int b   = row / Tt;
    const int len = msl[b];
    float* p = s + (long)row * Mm;
    const int tid = threadIdx.x;

    float v[2], mx = -INFINITY;
#pragma unroll
    for (int q = 0; q < 2; ++q) {
        int m = tid + q * 256;
        v[q] = (m < len) ? p[m] : -INFINITY;
        mx = fmaxf(mx, v[q]);
    }
    red[tid] = mx; __syncthreads();
    for (int off = 128; off > 0; off >>= 1) {
        if (tid < off) red[tid] = fmaxf(red[tid], red[tid + off]);
        __syncthreads();
    }
    mx = red[0]; __syncthreads();

    float e[2], sm = 0.f;
#pragma unroll
    for (int q = 0; q < 2; ++q) {
        int m = tid + q * 256;
        e[q] = (m < len) ? expf(v[q] - mx) : 0.f;
        sm += e[q];
    }
    red[tid] = sm; __syncthreads();
    for (int off = 128; off > 0; off >>= 1) {
        if (tid < off) red[tid] += red[tid + off];
        __syncthreads();
    }
    const float inv = 1.0f / red[0];
#pragma unroll
    for (int q = 0; q < 2; ++q) p[tid + q * 256] = e[q] * inv;
}

// ---- zero rowsum + pgacc ----------------------------------------------------
__global__ void init_zero(float* __restrict__ rowsum, float* __restrict__ pgacc)
{
    int i = blockIdx.x * 256 + threadIdx.x;
    if (i < NN) { rowsum[i] = 0.f; pgacc[i] = 0.f; }
}

// ---- pg = sigmoid(pgacc + bg); linv = log(pg / rowsum) ----------------------
__global__ void linv_pg(const float* __restrict__ pgacc, const float* __restrict__ bg,
                        const float* __restrict__ rowsum,
                        float* __restrict__ pg, float* __restrict__ linv)
{
    int i = blockIdx.x * 256 + threadIdx.x;
    if (i < NN) {
        float p = 1.0f / (1.0f + __expf(-(pgacc[i] + bg[0])));
        pg[i] = p;
        linv[i] = __logf(p / rowsum[i]);
    }
}

// ---- fused: out[row][*] += linv[row]; then copy fix-up on <=512 positions ---
__launch_bounds__(256)
__global__ void shift_fix(float* __restrict__ out, const float* __restrict__ attn,
                          const float* __restrict__ pg, const int* __restrict__ ids,
                          const int* __restrict__ msl, const float* __restrict__ linv)
{
    __shared__ int   ids_s[Mm];
    __shared__ float vals_s[Mm];
    const int row = blockIdx.x;
    const int b   = row / Tt;
    const int len = msl[b];
    const int tid = threadIdx.x;
    const float s = linv[row];
    const float c = 1.0f - pg[row];

    for (int m = tid; m < len; m += 256) {
        ids_s[m]  = ids[(long)b * Mm + m];
        vals_s[m] = attn[(long)row * Mm + m] * c;
    }

    float* p = out + (long)row * Vv;
    const int mis  = (int)(((unsigned)((long)row * Vv)) & 3u);
    const int head = (4 - mis) & 3;
    if (tid < head) p[tid] += s;
    const int nv = (Vv - head) >> 2;
    float4* p4 = (float4*)(p + head);
    for (int i = tid; i < nv; i += 256) {
        float4 v = p4[i];
        v.x += s; v.y += s; v.z += s; v.w += s;
        p4[i] = v;
    }
    const int t = head + nv * 4 + tid;
    if (t < Vv) p[t] += s;

    __syncthreads();

    for (int m = tid; m < len; m += 256) {
        const int id = ids_s[m];
        bool first = true;
        float tot = vals_s[m];
        for (int m2 = 0; m2 < len; ++m2) {
            if (ids_s[m2] == id) {
                if (m2 < m) { first = false; break; }
                if (m2 > m) tot += vals_s[m2];
            }
        }
        if (first) p[id] = __logf(__expf(p[id]) + tot);
    }
}

extern "C" void kernel_launch(void* const* d_in, const int* in_sizes, int n_in,
                              void* d_out, int out_size, void* d_ws, size_t ws_size,
                              hipStream_t stream)
{
    const float* dec = (const float*)d_in[0];
    const float* mem = (const float*)d_in[1];
    const int*   msl = (const int*)d_in[2];
    const int*   ids = (const int*)d_in[3];
    const float* Wc  = (const float*)d_in[4];
    // d_in[5] = b_copy: per-(b,t)-constant shift of scores -> softmax-invariant; skip.
    const float* Wd  = (const float*)d_in[6];
    const float* bd  = (const float*)d_in[7];
    const float* Wg  = (const float*)d_in[8];
    const float* bg  = (const float*)d_in[9];
    const float* Wo  = (const float*)d_in[10];
    const float* bo  = (const float*)d_in[11];

    float* out = (float*)d_out;

    // ---- ws layout (~107 MB, verified to fit in round 4) ----
    float* ws     = (float*)d_ws;
    float* attn   = ws;                          // NN*Mm fp32 (survives to shift_fix)
    float* pg     = attn + (size_t)NN * Mm;
    float* linv   = pg + NN;
    float* rowsum = linv + NN;
    float* pgacc  = rowsum + NN;
    ushort* A16   = (ushort*)(pgacc + NN);       // dec_hi  NN*Dd
    ushort* B16   = A16 + (size_t)NN * Dd;       // W_out   Vv*Dd

    // ---- d_out doubles as scratch; everything consumed before logits GEMM ----
    ushort* S      = (ushort*)d_out;
    ushort* dec_lo = S;
    ushort* WcT_hi = dec_lo + (size_t)NN * Dd;
    ushort* WcT_lo = WcT_hi + (size_t)Dd * Dd;
    ushort* mem_hi = WcT_lo + (size_t)Dd * Dd;
    ushort* mem_lo = mem_hi + (size_t)Bb * Mm * Dd;
    ushort* memT16 = mem_lo + (size_t)Bb * Mm * Dd;
    ushort* dp_hi  = memT16 + (size_t)Bb * Mm * Dd;
    ushort* dp_lo  = dp_hi + (size_t)NN * Dd;
    ushort* Wd16   = dp_lo + (size_t)NN * Dd;
    ushort* attn16 = Wd16 + (size_t)Dd * 2 * Dd;
    ushort* ao16   = attn16 + (size_t)NN * Mm;   // attn_out bf16
    float* dec_proj = (float*)(ao16 + (size_t)NN * Dd);

    // 0. init + precision prep
    init_zero<<<DIV_UP(NN,256), 256, 0, stream>>>(rowsum, pgacc);
    split_cast<<<256, 256, 0, stream>>>(dec, A16, dec_lo, (long)NN * Dd / 8);
    split_cast<<<512, 256, 0, stream>>>(mem, mem_hi, mem_lo, (long)Bb * Mm * Dd / 8);
    transpose_split<<<dim3(Dd/32, Dd/32, 1), 256, 0, stream>>>(Wc, WcT_hi, WcT_lo, Dd, Dd);
    transpose_split<<<dim3(Dd/32, Mm/32, Bb), 256, 0, stream>>>(mem, memT16, nullptr, Mm, Dd);
    cast_bf16<<<512, 256, 0, stream>>>(Wd, Wd16, (long)Dd * 2 * Dd / 8);
    cast_bf16<<<2048, 256, 0, stream>>>(Wo, B16, (long)Vv * Dd / 8);

    // 1. dec_proj = dec @ W_copy^T-form (split-bf16, ~fp32 accuracy)
    gemm_mx<true><<<dim3(Dd/128, NN/128, 1), 256, 0, stream>>>(
        A16, dec_lo, WcT_hi, WcT_lo, A16, Dd, Dd, nullptr,
        dec_proj, nullptr, nullptr, nullptr,
        Dd, Dd, Dd, Dd, Dd, 0, 0, 0, 0, 0);
    split_cast<<<256, 256, 0, stream>>>(dec_proj, dp_hi, dp_lo, (long)NN * Dd / 8);

    // 2. scores[b] = dec_proj[b] @ mem[b]^T (split-bf16, batched)
    gemm_mx<true><<<dim3(Mm/128, Tt/128, Bb), 256, 0, stream>>>(
        dp_hi, dp_lo, mem_hi, mem_lo, dp_hi, Dd, Dd, nullptr,
        attn, nullptr, nullptr, nullptr,
        Mm, Dd, Dd, Dd, Mm, (long)Tt*Dd, (long)Mm*Dd, (long)Tt*Mm, 0, 0);

    // 3. masked softmax (fp32)
    softmax_rows<<<NN, 256, 0, stream>>>(attn, msl);
    cast_bf16<<<128, 256, 0, stream>>>(attn, attn16, (long)NN * Mm / 8);

    // 4. attn_out16[b] = attn[b] @ mem[b] (bf16; feeds only p_gen)
    gemm_mx<false><<<dim3(Dd/128, Tt/128, Bb), 256, 0, stream>>>(
        attn16, attn16, memT16, memT16, attn16, Mm, Mm, nullptr,
        nullptr, ao16, nullptr, nullptr,
        Dd, Mm, Mm, Mm, Dd, (long)Tt*Mm, (long)Dd*Mm, (long)Tt*Dd, 4, 0);

    // 5+6. pgacc[row] = sum_d tanh(([dec|attn_out] @ Wd^T + bd)[row,d]) * Wg[d]
    gemm_mx<false><<<dim3(Dd/128, NN/128, 1), 256, 0, stream>>>(
        A16, A16, Wd16, Wd16, ao16, Dd, Dd, bd,
        nullptr, nullptr, pgacc, Wg,
        Dd, 2*Dd, Dd, 2*Dd, 0, 0, 0, 0, 2, 0);

    // 7. logits = dec @ W_out^T + b_out -> out; rowsum += sum(exp). XCD-swizzled.
    gemm_mx<false><<<8 * 8 * DIV_UP(DIV_UP(Vv,128), 8), 256, 0, stream>>>(
        A16, A16, B16, B16, A16, Dd, Dd, bo,
        out, nullptr, rowsum, nullptr,
        Vv, Dd, Dd, Dd, Vv, 0, 0, 0, 1, DIV_UP(Vv,128));

    // 8. pg + linv
    linv_pg<<<DIV_UP(NN,256), 256, 0, stream>>>(pgacc, bg, rowsum, pg, linv);

    // 9. fused shift + copy fix-up
    shift_fix<<<NN, 256, 0, stream>>>(out, attn, pg, ids, msl, linv);
}